// Round 9
// baseline (10320.904 us; speedup 1.0000x reference)
//
#include <hip/hip_runtime.h>

#define TT 1024

typedef _Float16 f16;
typedef _Float16 f16x8 __attribute__((ext_vector_type(8)));
typedef float f32x4 __attribute__((ext_vector_type(4)));
typedef unsigned long long u64;
typedef unsigned u32;

__device__ __forceinline__ float sigmoidf_(float x) { return 1.0f / (1.0f + __expf(-x)); }
__device__ __forceinline__ float tanhf_(float x) { return 1.0f - 2.0f / (__expf(2.0f * x) + 1.0f); }

// Tagged u64 element: lo32 = packed f16 pair (2 adjacent hidden units), hi32 = epoch
// tag. ONE 8B agent-scope atomic store publishes data+tag indivisibly, so a reader
// that sees the expected tag provably holds that epoch's data: no flags, no release
// drains, no barrier. Agent 8B atomics are the r0-baseline-proven primitive.
__device__ __forceinline__ void load_chunk4(const u64* p, u64* w) {
#pragma unroll
  for (int j = 0; j < 4; ++j)
    w[j] = __hip_atomic_load(p + j, __ATOMIC_RELAXED, __HIP_MEMORY_SCOPE_AGENT);
}
__device__ __forceinline__ bool tags_ok4(const u64* w, u32 ex) {
  bool ok = true;
#pragma unroll
  for (int j = 0; j < 4; ++j) ok = ok && ((u32)(w[j] >> 32) == ex);
  return ok;
}
__device__ __forceinline__ f16x8 pack_frag4(const u64* w) {
  union { u32 u[4]; f16x8 f; } r;
#pragma unroll
  for (int j = 0; j < 4; ++j) r.u[j] = (u32)w[j];
  return r.f;
}

// Dataflow LSTM layer. Geometry (r6-proven): 8 groups x (16 L0-WG + 16 L1-WG); group
// owns 32 batch rows; WG owns 16 units; per-wave MFMA micro-structure unchanged.
// Buffers (u64-tagged): h1 6-deep (write buf (it-1)%6, read (it+4)%6), h2 2-deep
// (write (it-1)&1, read it&1). Tags: L0 stores tag=it, L1 stores tag=it-1.
// Expected: h1 readers -> it-1; h2 readers -> it-2. Memset-zero of h1 buf5 + h2 buf0
// supplies the t<0 zero states with tag 0 = exactly the first expected tags.
// Overwrite safety: within a layer, a WG reaching iter it+1 has OBSERVED all peers'
// iter-it stores, which (program order) follow their iter-it reads -> no reader of
// old content remains. Cross-layer (L0 lapping L1 on h1): L1 posts per-wave progress
// flags (agent store, off critical path); L0 blocks iff minL1 < it-5 (6-deep h1),
// checked via a 1-iter-pipelined sample so the agent RT never sits on the fast path.
// All poll loops are capped (bug => wrong answer, never a hang).
template <int LAYER>
__device__ void run_layer(const float* __restrict__ xin,
                          const float* __restrict__ Wih, const float* __restrict__ Whh,
                          const float* __restrict__ bias,
                          u64* __restrict__ h1q, u64* __restrict__ h2q,
                          u32* __restrict__ Fg, int ng, int b0r,
                          float (*Gs)[68], int tid) {
  constexpr int NCH = (LAYER == 0) ? 12 : 16;
  constexpr int DIN = (LAYER == 0) ? 128 : 256;

  const int lane = tid & 63, wave = tid >> 6;
  const int q = lane >> 4, mm = lane & 15;
  const int rw = wave & 1, uw = wave >> 1;
  const int u0 = ng * 16 + uw * 8;

  // epilogue mapping: each thread owns 1 batch row x 2 adjacent units
  const int up_e = tid & 7, bl_e = tid >> 3;
  const int uwe = up_e >> 2, ppe = up_e & 3;
  const int uc0 = ng * 16 + uwe * 8 + 2 * ppe, uc1 = uc0 + 1;
  const int gcol = uwe * 32 + 2 * ppe;
  const float bi0 = bias[uc0],       bi1 = bias[uc1];
  const float bf0 = bias[256 + uc0], bf1 = bias[256 + uc1];
  const float bg0 = bias[512 + uc0], bg1 = bias[512 + uc1];
  const float bo0 = bias[768 + uc0], bo1 = bias[768 + uc1];

  // B-fragment preload: B[k=(lane>>4)*8+j][n=lane&15], W row = gate*256 + unit
  const int row0 = ((mm >> 3)) * 256 + u0 + (mm & 7);      // gates i,f
  const int row1 = ((mm >> 3) + 2) * 256 + u0 + (mm & 7);  // gates g,o
  f16x8 bA[NCH], bB[NCH];
#pragma unroll
  for (int c = 0; c < NCH; ++c) {
    const int k0 = c * 32 + q * 8;
    const float* s0 = (c < 8) ? (Whh + row0 * 256 + k0) : (Wih + row0 * DIN + (k0 - 256));
    const float* s1 = (c < 8) ? (Whh + row1 * 256 + k0) : (Wih + row1 * DIN + (k0 - 256));
    f16x8 v0, v1;
#pragma unroll
    for (int j = 0; j < 8; ++j) { v0[j] = (f16)s0[j]; v1[j] = (f16)s1[j]; }
    bA[c] = v0; bB[c] = v1;
  }

  float cA = 0.f, cB = 0.f;
  const int brow = b0r + rw * 16 + mm;

  float4 axr[8];   // raw fp32 x for the NEXT step (in flight across iters)
  f16x8 ax[4];     // fp16 x fragments for the CURRENT step
  u32 g_pend = 0;  // pipelined L1-progress sample (L0 only)

  for (int it = 0; it <= TT + 1; ++it) {
    const int i = it - 1;
    const bool active = (LAYER == 0) ? (i >= 0 && i < TT) : (i >= 1 && i <= TT);

    // ---- L0 overwrite gate (rarely binding; sample pipelined across iters)
    if (LAYER == 0) {
      const u32 cur = g_pend;
      g_pend = __hip_atomic_load(Fg + lane * 16, __ATOMIC_RELAXED, __HIP_MEMORY_SCOPE_AGENT);
      const int need = it - 5;
      if (need > 0 && !__all((int)cur >= need)) {
        for (int k = 0; k < (1 << 22); ++k) {
          u32 f = __hip_atomic_load(Fg + lane * 16, __ATOMIC_RELAXED, __HIP_MEMORY_SCOPE_AGENT);
          if (__all((int)f >= need)) break;
          __builtin_amdgcn_s_sleep(2);
        }
      }
    }

    if (LAYER == 0 && active) {
      // convert last iteration's raw x (issued one iter ago; auto-waited here)
#pragma unroll
      for (int c = 0; c < 4; ++c) {
        const float4 fa = axr[2 * c], fb = axr[2 * c + 1];
        f16x8 v; v[0]=(f16)fa.x; v[1]=(f16)fa.y; v[2]=(f16)fa.z; v[3]=(f16)fa.w;
        v[4]=(f16)fb.x; v[5]=(f16)fb.y; v[6]=(f16)fb.z; v[7]=(f16)fb.w;
        ax[c] = v;
      }
    }

    if (active) {
      const u64* h1r = h1q + (u64)((it + 4) % 6) * 32768 + brow * 128;
      const u64* h2r = h2q + (u64)(it & 1) * 32768 + brow * 128;   // L1 only
      const u32 e1 = (u32)(it - 1), e2 = (u32)(it - 2);

      // issue first 8 tagged chunks (pipelined; depth 8)
      u64 wb[8][4];
#pragma unroll
      for (int c = 0; c < 8; ++c) {
        const u64* cp = (LAYER == 0) ? (h1r + c * 16 + q * 4) : (h2r + c * 16 + q * 4);
        load_chunk4(cp, wb[c]);
      }

      // x prefetch for next iter (after chunk issues: chunk waits don't drain x)
      if (LAYER == 0 && it < TT) {
        const float* px = xin + (brow * 1024 + it) * 128 + q * 8;
#pragma unroll
        for (int c = 0; c < 4; ++c) {
          axr[2 * c]     = *(const float4*)(px + c * 32);
          axr[2 * c + 1] = *(const float4*)(px + c * 32 + 4);
        }
      }

      f32x4 acc0 = {0.f, 0.f, 0.f, 0.f}, acc1 = {0.f, 0.f, 0.f, 0.f};
#pragma unroll
      for (int c = 0; c < NCH; ++c) {
        f16x8 a;
        if (LAYER == 0 && c >= 8) {
          a = ax[c - 8];
        } else {
          const u32 ex = (LAYER == 0) ? e1 : (c < 8 ? e2 : e1);
          const u64* cp = (LAYER == 0) ? (h1r + c * 16 + q * 4)
                        : (c < 8 ? (h2r + c * 16 + q * 4) : (h1r + (c - 8) * 16 + q * 4));
          for (int k = 0;; ++k) {
            if (__all(tags_ok4(wb[c & 7], ex))) break;
            if (k >= (1 << 22)) break;          // hang insurance: fail loud, not silent
            __builtin_amdgcn_s_sleep(1);
            load_chunk4(cp, wb[c & 7]);
          }
          a = pack_frag4(wb[c & 7]);
          if (LAYER == 1 && c < 8)              // slot freed -> issue chunk c+8 (h1)
            load_chunk4(h1r + c * 16 + q * 4, wb[c & 7]);
        }
        acc0 = __builtin_amdgcn_mfma_f32_16x16x32_f16(a, bA[c], acc0, 0, 0, 0);
        acc1 = __builtin_amdgcn_mfma_f32_16x16x32_f16(a, bB[c], acc1, 0, 0, 0);
      }

      // gate exchange via LDS (r6-proven layout, stride 68)
#pragma unroll
      for (int r = 0; r < 4; ++r) {
        Gs[rw * 16 + q * 4 + r][uw * 32 + mm] = acc0[r];
        Gs[rw * 16 + q * 4 + r][uw * 32 + 16 + mm] = acc1[r];
      }
      __syncthreads();
      const float gi0 = Gs[bl_e][gcol]      + bi0, gi1 = Gs[bl_e][gcol + 1]  + bi1;
      const float gf0 = Gs[bl_e][gcol + 8]  + bf0, gf1 = Gs[bl_e][gcol + 9]  + bf1;
      const float gg0 = Gs[bl_e][gcol + 16] + bg0, gg1 = Gs[bl_e][gcol + 17] + bg1;
      const float go0 = Gs[bl_e][gcol + 24] + bo0, go1 = Gs[bl_e][gcol + 25] + bo1;
      __syncthreads();   // cheap (no VMEM outstanding); protects Gs vs next iter writes
      cA = sigmoidf_(gf0) * cA + sigmoidf_(gi0) * tanhf_(gg0);
      cB = sigmoidf_(gf1) * cB + sigmoidf_(gi1) * tanhf_(gg1);
      union { f16 h2v[2]; u32 u; } pk;
      pk.h2v[0] = (f16)(sigmoidf_(go0) * tanhf_(cA));
      pk.h2v[1] = (f16)(sigmoidf_(go1) * tanhf_(cB));
      u64* hq = (LAYER == 0) ? (h1q + (u64)((it - 1) % 6) * 32768)
                             : (h2q + (u64)((it - 1) & 1) * 32768);
      const u32 tg = (LAYER == 0) ? (u32)it : (u32)(it - 1);
      const u64 pv = ((u64)tg << 32) | (u64)pk.u;
      __hip_atomic_store(hq + (b0r + bl_e) * 128 + (uc0 >> 1), pv,
                         __ATOMIC_RELAXED, __HIP_MEMORY_SCOPE_AGENT);
    }

    // L1 progress flag (covers this wave's h1 READS, which precede its stores)
    if (LAYER == 1 && lane == 0)
      __hip_atomic_store(Fg + (ng * 4 + wave) * 16, (u32)it,
                         __ATOMIC_RELAXED, __HIP_MEMORY_SCOPE_AGENT);
  }
}

__global__ __launch_bounds__(256, 1) void lstm_persistent(
    const float* __restrict__ x,
    const float* __restrict__ Wih0, const float* __restrict__ Whh0, const float* __restrict__ b0v,
    const float* __restrict__ Wih1, const float* __restrict__ Whh1, const float* __restrict__ b1v,
    u64* h1q, u64* h2q, u32* F) {
  __shared__ float Gs[32][68];
  const int tid = threadIdx.x, bid = blockIdx.x;
  // fixed mapping (no XCD machinery): group = bid>>5 owns rows group*32..+31
  const int g = bid >> 5, r = bid & 31;
  const int layer = r >> 4, ng = r & 15, b0r = g * 32;
  u32* Fg = F + g * 1024;   // 64 wave-slots x 16 u32 (64B apart) per group

  if (layer == 0)
    run_layer<0>(x, Wih0, Whh0, b0v, h1q, h2q, Fg, ng, b0r, Gs, tid);
  else
    run_layer<1>(nullptr, Wih1, Whh1, b1v, h1q, h2q, Fg, ng, b0r, Gs, tid);
}

// final dense (C=10) + softmax on h2[T-1] (tagged u64 layout, low u32 = data)
__global__ __launch_bounds__(64, 1) void dense_softmax_k(const u64* __restrict__ h2,
                                                         const float* __restrict__ Wd,
                                                         const float* __restrict__ bd,
                                                         float* __restrict__ out) {
  const int b = blockIdx.x, lane = threadIdx.x;
  float hv[4];
#pragma unroll
  for (int j = 0; j < 4; ++j) {
    const int unit = lane + 64 * j;
    union { u32 u; f16 h[2]; } t;
    t.u = (u32)h2[b * 128 + (unit >> 1)];
    hv[j] = (float)t.h[unit & 1];
  }
  float p[10];
#pragma unroll
  for (int c = 0; c < 10; ++c) {
    float s = 0.f;
#pragma unroll
    for (int j = 0; j < 4; ++j) s += hv[j] * Wd[c * 256 + lane + 64 * j];
#pragma unroll
    for (int off = 32; off >= 1; off >>= 1) s += __shfl_xor(s, off, 64);
    p[c] = s;
  }
  if (lane == 0) {
    float mx = -1e30f;
#pragma unroll
    for (int c = 0; c < 10; ++c) { p[c] += bd[c]; mx = fmaxf(mx, p[c]); }
    float den = 0.f;
#pragma unroll
    for (int c = 0; c < 10; ++c) { p[c] = __expf(p[c] - mx); den += p[c]; }
#pragma unroll
    for (int c = 0; c < 10; ++c) out[b * 10 + c] = p[c] / den;
  }
}

extern "C" void kernel_launch(void* const* d_in, const int* in_sizes, int n_in,
                              void* d_out, int out_size, void* d_ws, size_t ws_size,
                              hipStream_t stream) {
  const float* x    = (const float*)d_in[0];
  const float* Wih0 = (const float*)d_in[1];
  const float* Whh0 = (const float*)d_in[2];
  const float* b0v  = (const float*)d_in[3];
  const float* Wih1 = (const float*)d_in[4];
  const float* Whh1 = (const float*)d_in[5];
  const float* b1v  = (const float*)d_in[6];
  const float* Wd   = (const float*)d_in[7];
  const float* bd   = (const float*)d_in[8];

  char* ws = (char*)d_ws;
  // layout: h1 tagged 6 x 256KB @0 (1.5MB) | h2 tagged 2 x 256KB @1.5MB | flags @2MB
  u64* h1q = (u64*)(ws);
  u64* h2q = (u64*)(ws + 1536 * 1024);
  u32* F   = (u32*)(ws + 2048 * 1024);

  // zero h1 buf5 (t<0 state, tag 0) + h2 buf0 (t<0 state, tag 0): contiguous 512KB;
  // and all progress flags (32KB).
  hipMemsetAsync(ws + 1280 * 1024, 0, 512 * 1024, stream);
  hipMemsetAsync(ws + 2048 * 1024, 0, 32 * 1024, stream);

  lstm_persistent<<<256, 256, 0, stream>>>(x, Wih0, Whh0, b0v, Wih1, Whh1, b1v,
                                           h1q, h2q, F);
  // h2 final state (iter TT+1, tag TT) lands in buf 0
  dense_softmax_k<<<256, 64, 0, stream>>>(h2q, Wd, bd, (float*)d_out);
}

// Round 10
// 4163.310 us; speedup vs baseline: 2.4790x; 2.4790x over previous
//
#include <hip/hip_runtime.h>

#define TT 1024

typedef _Float16 f16;
typedef _Float16 f16x8 __attribute__((ext_vector_type(8)));
typedef float f32x4 __attribute__((ext_vector_type(4)));
typedef unsigned long long u64;

__device__ __forceinline__ float sigmoidf_(float x) { return 1.0f / (1.0f + __expf(-x)); }
__device__ __forceinline__ float tanhf_(float x) { return 1.0f - 2.0f / (__expf(2.0f * x) + 1.0f); }

// ---------------- agent-scope load (proven; memory-side coherent, any placement) ------
__device__ __forceinline__ f16x8 load_frag_agent(const f16* p) {
  union { u64 v[2]; f16x8 f; } u;
  u.v[0] = __hip_atomic_load((u64*)p,     __ATOMIC_RELAXED, __HIP_MEMORY_SCOPE_AGENT);
  u.v[1] = __hip_atomic_load((u64*)p + 1, __ATOMIC_RELAXED, __HIP_MEMORY_SCOPE_AGENT);
  return u.f;
}

// ---------------- XCD-local loads: sc0 (r2-proven pair: plain store -> sc0 load) ------
// s_waitcnt vmcnt(0) INSIDE the asm: outputs complete when the block retires (rule #18
// safe). Frag spacing 32 f16 = 64 B.
__device__ __forceinline__ void load_h8_sc0(const f16* p, f16x8* a) {
  asm volatile(
      "global_load_dwordx4 %0, %8, off sc0\n\t"
      "global_load_dwordx4 %1, %8, off offset:64 sc0\n\t"
      "global_load_dwordx4 %2, %8, off offset:128 sc0\n\t"
      "global_load_dwordx4 %3, %8, off offset:192 sc0\n\t"
      "global_load_dwordx4 %4, %8, off offset:256 sc0\n\t"
      "global_load_dwordx4 %5, %8, off offset:320 sc0\n\t"
      "global_load_dwordx4 %6, %8, off offset:384 sc0\n\t"
      "global_load_dwordx4 %7, %8, off offset:448 sc0\n\t"
      "s_waitcnt vmcnt(0)"
      : "=&v"(a[0]), "=&v"(a[1]), "=&v"(a[2]), "=&v"(a[3]),
        "=&v"(a[4]), "=&v"(a[5]), "=&v"(a[6]), "=&v"(a[7])
      : "v"(p)
      : "memory");
}
__device__ __forceinline__ void load_h16_sc0(const f16* p0, const f16* p1, f16x8* a) {
  asm volatile(
      "global_load_dwordx4 %0, %16, off sc0\n\t"
      "global_load_dwordx4 %1, %16, off offset:64 sc0\n\t"
      "global_load_dwordx4 %2, %16, off offset:128 sc0\n\t"
      "global_load_dwordx4 %3, %16, off offset:192 sc0\n\t"
      "global_load_dwordx4 %4, %16, off offset:256 sc0\n\t"
      "global_load_dwordx4 %5, %16, off offset:320 sc0\n\t"
      "global_load_dwordx4 %6, %16, off offset:384 sc0\n\t"
      "global_load_dwordx4 %7, %16, off offset:448 sc0\n\t"
      "global_load_dwordx4 %8, %17, off sc0\n\t"
      "global_load_dwordx4 %9, %17, off offset:64 sc0\n\t"
      "global_load_dwordx4 %10, %17, off offset:128 sc0\n\t"
      "global_load_dwordx4 %11, %17, off offset:192 sc0\n\t"
      "global_load_dwordx4 %12, %17, off offset:256 sc0\n\t"
      "global_load_dwordx4 %13, %17, off offset:320 sc0\n\t"
      "global_load_dwordx4 %14, %17, off offset:384 sc0\n\t"
      "global_load_dwordx4 %15, %17, off offset:448 sc0\n\t"
      "s_waitcnt vmcnt(0)"
      : "=&v"(a[0]), "=&v"(a[1]), "=&v"(a[2]), "=&v"(a[3]),
        "=&v"(a[4]), "=&v"(a[5]), "=&v"(a[6]), "=&v"(a[7]),
        "=&v"(a[8]), "=&v"(a[9]), "=&v"(a[10]), "=&v"(a[11]),
        "=&v"(a[12]), "=&v"(a[13]), "=&v"(a[14]), "=&v"(a[15])
      : "v"(p0), "v"(p1)
      : "memory");
}

// Group barrier over 16 WGs — r6's proven mechanics verbatim (agent store arrive,
// agent load poll, sleep(2)); only the slot count changed (16). Relaxed thresholds
// (r6-proven): L0 waits L0 slots (0..7) >= e, L1 slots (8..15) >= e-1 (h1 is
// triple-buffered -> one step of write-safety slack); L1 waits all >= e.
template <int LAYER>
__device__ __forceinline__ void group_barrier(unsigned* slots, int role, unsigned e, int tid) {
  __syncthreads();
  __atomic_signal_fence(__ATOMIC_SEQ_CST);
  if (tid == 0)
    __hip_atomic_store(slots + role * 64, e, __ATOMIC_RELAXED, __HIP_MEMORY_SCOPE_AGENT);
  if (tid < 64) {
    const int s = tid & 15;
    const unsigned thr = (LAYER == 0 && s >= 8) ? e - 1u : e;
    for (;;) {
      unsigned v = __hip_atomic_load(slots + s * 64, __ATOMIC_RELAXED,
                                     __HIP_MEMORY_SCOPE_AGENT);
      if (__all(v >= thr)) break;
      __builtin_amdgcn_s_sleep(2);
    }
  }
  __atomic_signal_fence(__ATOMIC_SEQ_CST);
  __syncthreads();
}

// One LSTM layer's persistent loop. NEW geometry: 8 groups x (8 L0-WG + 8 L1-WG);
// each group owns 32 batch rows; each WG owns 32 hidden units (was 16) -> halves the
// per-step redundant sc0 h re-read volume per XCD and shrinks the barrier straggler
// set 32 -> 16. Per wave (rw=wave&1 row-block, uw=wave>>1 16-unit half): TWO 8-unit
// sub-blocks, each with the r6-proven MFMA micro-structure (i/f in bA, g/o in bB,
// C/D col=lane&15, row=(lane>>4)*4+reg). All transport r6-verbatim: LOCAL = plain h
// stores + sc0 h loads; !LOCAL = agent data path. h1 3-buffered, h2 2-buffered.
template <int LAYER, bool LOCAL>
__device__ void run_layer(const float* __restrict__ xin, const f16* __restrict__ in2base,
                          const float* __restrict__ Wih, const float* __restrict__ Whh,
                          const float* __restrict__ bias, f16* __restrict__ hself,
                          unsigned* slots, int role, int ng, int b0r,
                          float (*Gs)[132], int tid) {
  constexpr int NCH = (LAYER == 0) ? 12 : 16;
  constexpr int DIN = (LAYER == 0) ? 128 : 256;

  const int lane = tid & 63, wave = tid >> 6;
  const int q = lane >> 4, mm = lane & 15;
  const int rw = wave & 1, uw = wave >> 1;

  // epilogue mapping: thread owns batch row (tid>>3) x 4 adjacent units (8B store)
  const int er = tid >> 3, up = tid & 7;
  const int ubl = 4 * up;                      // WG-local unit base 0..28
  const int uc0 = ng * 32 + ubl;               // global unit base
  const int pcol = (ubl >> 3) * 32 + (ubl & 7);  // Gs col of gate-i for these units
  const float4 bi4 = *(const float4*)(bias + uc0);
  const float4 bf4 = *(const float4*)(bias + 256 + uc0);
  const float4 bg4 = *(const float4*)(bias + 512 + uc0);
  const float4 bo4 = *(const float4*)(bias + 768 + uc0);

  // B-fragment preload, 2 sub-blocks of 8 units: B[k=(lane>>4)*8+j][n=lane&15],
  // W row = gate*256 + unit (gates i,f in bA; g,o in bB) — r6 layout per sub-block.
  f16x8 bA[2][NCH], bB[2][NCH];
#pragma unroll
  for (int sub = 0; sub < 2; ++sub) {
    const int u0s = ng * 32 + uw * 16 + sub * 8;
    const int row0 = ((mm >> 3)) * 256 + u0s + (mm & 7);
    const int row1 = ((mm >> 3) + 2) * 256 + u0s + (mm & 7);
#pragma unroll
    for (int c = 0; c < NCH; ++c) {
      const int k0 = c * 32 + q * 8;
      const float* s0 = (c < 8) ? (Whh + row0 * 256 + k0) : (Wih + row0 * DIN + (k0 - 256));
      const float* s1 = (c < 8) ? (Whh + row1 * 256 + k0) : (Wih + row1 * DIN + (k0 - 256));
      f16x8 v0, v1;
#pragma unroll
      for (int j = 0; j < 8; ++j) { v0[j] = (f16)s0[j]; v1[j] = (f16)s1[j]; }
      bA[sub][c] = v0; bB[sub][c] = v1;
    }
  }

  float c0 = 0.f, c1 = 0.f, c2 = 0.f, c3 = 0.f;  // 4 owned cell states, registers
  const int brow = b0r + rw * 16 + mm;

  float4 axr[8];   // raw fp32 x for the NEXT step (loaded 1 iter ahead)
  f16x8 ax[4];     // fp16 x fragments for the CURRENT step

  for (int it = 0; it <= TT + 1; ++it) {
    const int i = it - 1;
    const bool active = (LAYER == 0) ? (i >= 0 && i < TT) : (i >= 1 && i <= TT);

    if (LAYER == 0 && active) {
      // convert last iteration's raw x (drained at the intervening barrier)
#pragma unroll
      for (int c = 0; c < 4; ++c) {
        const float4 fa = axr[2 * c], fb = axr[2 * c + 1];
        f16x8 v; v[0]=(f16)fa.x; v[1]=(f16)fa.y; v[2]=(f16)fa.z; v[3]=(f16)fa.w;
        v[4]=(f16)fb.x; v[5]=(f16)fb.y; v[6]=(f16)fb.z; v[7]=(f16)fb.w;
        ax[c] = v;
      }
    }

    f16x8 a[NCH];
    if (active) {
      // L0: own h1, 3-buffer, read (i+2)%3.  L1: own h2 2-buffer; input h1 (i+2)%3.
      const f16* hprev = (LAYER == 0) ? (hself + ((i + 2) % 3) * 65536)
                                      : (hself + ((i + 1) & 1) * 65536);
      const f16* pa1 = hprev + brow * 256 + q * 8;
      if (LAYER == 0) {
        if constexpr (LOCAL) load_h8_sc0(pa1, a);
        else {
#pragma unroll
          for (int c = 0; c < 8; ++c) a[c] = load_frag_agent(pa1 + c * 32);
        }
#pragma unroll
        for (int c = 8; c < NCH; ++c) a[c] = ax[c - 8];
      } else {
        const f16* pa2 = in2base + ((i + 2) % 3) * 65536 + brow * 256 + q * 8;
        if constexpr (LOCAL) load_h16_sc0(pa1, pa2, a);
        else {
#pragma unroll
          for (int c = 0; c < 8; ++c) a[c] = load_frag_agent(pa1 + c * 32);
#pragma unroll
          for (int c = 8; c < NCH; ++c) a[c] = load_frag_agent(pa2 + (c - 8) * 32);
        }
      }
    }

    // issue raw x loads for step `it` (consumed next iteration); after the h-load wait
    // so they stay in flight across MFMA/epilogue/barrier.
    if (LAYER == 0 && it < TT) {
      const float* px = xin + (brow * 1024 + it) * 128 + q * 8;
#pragma unroll
      for (int c = 0; c < 4; ++c) {
        axr[2 * c]     = *(const float4*)(px + c * 32);
        axr[2 * c + 1] = *(const float4*)(px + c * 32 + 4);
      }
    }

    if (active) {
      f32x4 ac[2][2];
#pragma unroll
      for (int sub = 0; sub < 2; ++sub) {
        ac[sub][0] = (f32x4){0.f, 0.f, 0.f, 0.f};
        ac[sub][1] = (f32x4){0.f, 0.f, 0.f, 0.f};
      }
#pragma unroll
      for (int c = 0; c < NCH; ++c) {
#pragma unroll
        for (int sub = 0; sub < 2; ++sub) {
          ac[sub][0] = __builtin_amdgcn_mfma_f32_16x16x32_f16(a[c], bA[sub][c], ac[sub][0], 0, 0, 0);
          ac[sub][1] = __builtin_amdgcn_mfma_f32_16x16x32_f16(a[c], bB[sub][c], ac[sub][1], 0, 0, 0);
        }
      }
      // Gs layout: per 8-unit block p = uw*2+sub, cols p*32 + {0-7:i, 8-15:f, 16-23:g,
      // 24-31:o}; row = batch row. C/D: col=lane&15, row=(lane>>4)*4+reg (proven).
#pragma unroll
      for (int sub = 0; sub < 2; ++sub) {
        const int p = uw * 2 + sub;
#pragma unroll
        for (int r = 0; r < 4; ++r) {
          Gs[rw * 16 + q * 4 + r][p * 32 + mm]      = ac[sub][0][r];
          Gs[rw * 16 + q * 4 + r][p * 32 + 16 + mm] = ac[sub][1][r];
        }
      }
      __syncthreads();
      {
        f16* hout = (LAYER == 0) ? (hself + (i % 3) * 65536)
                                 : (hself + (i & 1) * 65536);
        const float4 gi = *(const float4*)&Gs[er][pcol];
        const float4 gf = *(const float4*)&Gs[er][pcol + 8];
        const float4 gg = *(const float4*)&Gs[er][pcol + 16];
        const float4 go = *(const float4*)&Gs[er][pcol + 24];
        c0 = sigmoidf_(gf.x + bf4.x) * c0 + sigmoidf_(gi.x + bi4.x) * tanhf_(gg.x + bg4.x);
        c1 = sigmoidf_(gf.y + bf4.y) * c1 + sigmoidf_(gi.y + bi4.y) * tanhf_(gg.y + bg4.y);
        c2 = sigmoidf_(gf.z + bf4.z) * c2 + sigmoidf_(gi.z + bi4.z) * tanhf_(gg.z + bg4.z);
        c3 = sigmoidf_(gf.w + bf4.w) * c3 + sigmoidf_(gi.w + bi4.w) * tanhf_(gg.w + bg4.w);
        union { f16 h4[4]; u64 u; } pk;
        pk.h4[0] = (f16)(sigmoidf_(go.x + bo4.x) * tanhf_(c0));
        pk.h4[1] = (f16)(sigmoidf_(go.y + bo4.y) * tanhf_(c1));
        pk.h4[2] = (f16)(sigmoidf_(go.z + bo4.z) * tanhf_(c2));
        pk.h4[3] = (f16)(sigmoidf_(go.w + bo4.w) * tanhf_(c3));
        u64* dst = (u64*)(hout + (b0r + er) * 256 + uc0);
        if constexpr (LOCAL) {
          // plain write-through store: lands in own-XCD L2; drained (vmcnt 0) by the
          // barrier's __syncthreads BEFORE the agent flag store => release-ordered.
          *dst = pk.u;
        } else {
          __hip_atomic_store(dst, pk.u, __ATOMIC_RELAXED, __HIP_MEMORY_SCOPE_AGENT);
        }
      }
    }

    if (it <= TT) group_barrier<LAYER>(slots, role, (unsigned)(it + 1), tid);
  }
}

__global__ __launch_bounds__(256, 1) void lstm_persistent(
    const float* __restrict__ x,
    const float* __restrict__ Wih0, const float* __restrict__ Whh0, const float* __restrict__ b0v,
    const float* __restrict__ Wih1, const float* __restrict__ Whh1, const float* __restrict__ b1v,
    f16* h1buf, f16* h2buf, unsigned* F) {
  __shared__ float Gs[32][132];
  __shared__ int sh[3];
  const int tid = threadIdx.x;

  // ---- XCD self-organization (proven r2/r4/r6; claim threshold now 16/XCD).
  // NG (9 u32) at F[32..40]: padding inside group-0 slot 0 (flags at multiples of
  // 64 u32), zeroed by the slot memset — r6-proven placement.
  if (tid == 0) {
    // HW_REG_XCC_ID = hwreg id 20, offset 0, size 32 -> imm = 20 | (31<<11) = 63508
    unsigned xcc = __builtin_amdgcn_s_getreg(63508) & 7u;
    unsigned* NG = F + 32;
    unsigned rank = __hip_atomic_fetch_add(&NG[xcc], 1u, __ATOMIC_RELAXED, __HIP_MEMORY_SCOPE_AGENT);
    __hip_atomic_fetch_add(&NG[8], 1u, __ATOMIC_RELEASE, __HIP_MEMORY_SCOPE_AGENT);
    while (__hip_atomic_load(&NG[8], __ATOMIC_ACQUIRE, __HIP_MEMORY_SCOPE_AGENT) < 128u)
      __builtin_amdgcn_s_sleep(8);
    unsigned cnt[8];
#pragma unroll
    for (int xx = 0; xx < 8; ++xx)
      cnt[xx] = __hip_atomic_load(&NG[xx], __ATOMIC_RELAXED, __HIP_MEMORY_SCOPE_AGENT);
    int group, role2;
    if (rank < 16u) {
      group = (int)xcc; role2 = (int)rank;
    } else {
      // deterministic overflow assignment: my overflow index -> j-th deficit slot
      int ov = (int)rank - 16;
      for (int xx = 0; xx < (int)xcc; ++xx) ov += max(0, (int)cnt[xx] - 16);
      int gg = 0, acc = 0;
      for (gg = 0; gg < 8; ++gg) {
        const int d = 16 - min(16, (int)cnt[gg]);
        if (ov < acc + d) break;
        acc += d;
      }
      if (gg > 7) gg = 7;
      group = gg; role2 = min(15, (int)cnt[gg] + (ov - acc));
    }
    sh[0] = group; sh[1] = role2; sh[2] = (cnt[group] >= 16u) ? 1 : 0;  // fully local?
  }
  __syncthreads();
  const int group = sh[0], role = sh[1], local = sh[2];
  unsigned* slots = F + group * 2048;   // 16 slots x 64 u32 (256B apart) per group
  const int b0r = group * 32;
  const int layer = role >> 3, ng = role & 7;

  if (layer == 0) {
    if (local) run_layer<0, true >(x, nullptr, Wih0, Whh0, b0v, h1buf, slots, role, ng, b0r, Gs, tid);
    else       run_layer<0, false>(x, nullptr, Wih0, Whh0, b0v, h1buf, slots, role, ng, b0r, Gs, tid);
  } else {
    if (local) run_layer<1, true >(nullptr, h1buf, Wih1, Whh1, b1v, h2buf, slots, role, ng, b0r, Gs, tid);
    else       run_layer<1, false>(nullptr, h1buf, Wih1, Whh1, b1v, h2buf, slots, role, ng, b0r, Gs, tid);
  }
}

// final dense (C=10) + softmax on h2[T-1]; one wave per batch row.
// (kernel-end release flushes dirty h lines; standard inter-kernel visibility.)
__global__ __launch_bounds__(64, 1) void dense_softmax_k(const f16* __restrict__ h2,
                                                         const float* __restrict__ Wd,
                                                         const float* __restrict__ bd,
                                                         float* __restrict__ out) {
  const int b = blockIdx.x, lane = threadIdx.x;
  float hv[4];
#pragma unroll
  for (int j = 0; j < 4; ++j) hv[j] = (float)h2[b * 256 + lane + 64 * j];
  float p[10];
#pragma unroll
  for (int c = 0; c < 10; ++c) {
    float s = 0.f;
#pragma unroll
    for (int j = 0; j < 4; ++j) s += hv[j] * Wd[c * 256 + lane + 64 * j];
#pragma unroll
    for (int off = 32; off >= 1; off >>= 1) s += __shfl_xor(s, off, 64);
    p[c] = s;
  }
  if (lane == 0) {
    float mx = -1e30f;
#pragma unroll
    for (int c = 0; c < 10; ++c) { p[c] += bd[c]; mx = fmaxf(mx, p[c]); }
    float den = 0.f;
#pragma unroll
    for (int c = 0; c < 10; ++c) { p[c] = __expf(p[c] - mx); den += p[c]; }
#pragma unroll
    for (int c = 0; c < 10; ++c) out[b * 10 + c] = p[c] / den;
  }
}

extern "C" void kernel_launch(void* const* d_in, const int* in_sizes, int n_in,
                              void* d_out, int out_size, void* d_ws, size_t ws_size,
                              hipStream_t stream) {
  const float* x    = (const float*)d_in[0];
  const float* Wih0 = (const float*)d_in[1];
  const float* Whh0 = (const float*)d_in[2];
  const float* b0v  = (const float*)d_in[3];
  const float* Wih1 = (const float*)d_in[4];
  const float* Whh1 = (const float*)d_in[5];
  const float* b1v  = (const float*)d_in[6];
  const float* Wd   = (const float*)d_in[7];
  const float* bd   = (const float*)d_in[8];

  char* ws = (char*)d_ws;
  // layout: h1buf[3] @0 (384KB) | h2buf[2] @384K (256KB) | slots+NG @640K (64KB)
  f16* h1buf = (f16*)(ws);
  f16* h2buf = (f16*)(ws + 384 * 1024);
  unsigned* F = (unsigned*)(ws + 640 * 1024);

  // zero h1 buffer 2 (initial h1[-1], @256K) + h2 buffer 0 (initial h2 state, @384K)
  // -> contiguous 256KB; and all slots/NG.
  hipMemsetAsync(ws + 256 * 1024, 0, 256 * 1024, stream);
  hipMemsetAsync(ws + 640 * 1024, 0, 64 * 1024, stream);

  lstm_persistent<<<128, 256, 0, stream>>>(x, Wih0, Whh0, b0v, Wih1, Whh1, b1v,
                                           h1buf, h2buf, F);
  // h2[T-1] lands in h2buf[0] (T even)
  dense_softmax_k<<<256, 64, 0, stream>>>(h2buf, Wd, bd, (float*)d_out);
}

// Round 11
// 4110.210 us; speedup vs baseline: 2.5110x; 1.0129x over previous
//
#include <hip/hip_runtime.h>

#define TT 1024

typedef _Float16 f16;
typedef _Float16 f16x8 __attribute__((ext_vector_type(8)));
typedef float f32x4 __attribute__((ext_vector_type(4)));
typedef unsigned long long u64;

__device__ __forceinline__ float sigmoidf_(float x) { return 1.0f / (1.0f + __expf(-x)); }
__device__ __forceinline__ float tanhf_(float x) { return 1.0f - 2.0f / (__expf(2.0f * x) + 1.0f); }

// ---------------- agent-scope load (proven; memory-side coherent, any placement) ------
__device__ __forceinline__ f16x8 load_frag_agent(const f16* p) {
  union { u64 v[2]; f16x8 f; } u;
  u.v[0] = __hip_atomic_load((u64*)p,     __ATOMIC_RELAXED, __HIP_MEMORY_SCOPE_AGENT);
  u.v[1] = __hip_atomic_load((u64*)p + 1, __ATOMIC_RELAXED, __HIP_MEMORY_SCOPE_AGENT);
  return u.f;
}

// ---------------- XCD-local h loads: sc0 (r2-proven: works because h lines are evicted
// from L1 every step by the ~64KB step working set). waitcnt inside asm (rule #18 safe).
__device__ __forceinline__ void load_h8_sc0(const f16* p, f16x8* a) {
  asm volatile(
      "global_load_dwordx4 %0, %8, off sc0\n\t"
      "global_load_dwordx4 %1, %8, off offset:64 sc0\n\t"
      "global_load_dwordx4 %2, %8, off offset:128 sc0\n\t"
      "global_load_dwordx4 %3, %8, off offset:192 sc0\n\t"
      "global_load_dwordx4 %4, %8, off offset:256 sc0\n\t"
      "global_load_dwordx4 %5, %8, off offset:320 sc0\n\t"
      "global_load_dwordx4 %6, %8, off offset:384 sc0\n\t"
      "global_load_dwordx4 %7, %8, off offset:448 sc0\n\t"
      "s_waitcnt vmcnt(0)"
      : "=&v"(a[0]), "=&v"(a[1]), "=&v"(a[2]), "=&v"(a[3]),
        "=&v"(a[4]), "=&v"(a[5]), "=&v"(a[6]), "=&v"(a[7])
      : "v"(p)
      : "memory");
}
__device__ __forceinline__ void load_h16_sc0(const f16* p0, const f16* p1, f16x8* a) {
  asm volatile(
      "global_load_dwordx4 %0, %16, off sc0\n\t"
      "global_load_dwordx4 %1, %16, off offset:64 sc0\n\t"
      "global_load_dwordx4 %2, %16, off offset:128 sc0\n\t"
      "global_load_dwordx4 %3, %16, off offset:192 sc0\n\t"
      "global_load_dwordx4 %4, %16, off offset:256 sc0\n\t"
      "global_load_dwordx4 %5, %16, off offset:320 sc0\n\t"
      "global_load_dwordx4 %6, %16, off offset:384 sc0\n\t"
      "global_load_dwordx4 %7, %16, off offset:448 sc0\n\t"
      "global_load_dwordx4 %8, %17, off sc0\n\t"
      "global_load_dwordx4 %9, %17, off offset:64 sc0\n\t"
      "global_load_dwordx4 %10, %17, off offset:128 sc0\n\t"
      "global_load_dwordx4 %11, %17, off offset:192 sc0\n\t"
      "global_load_dwordx4 %12, %17, off offset:256 sc0\n\t"
      "global_load_dwordx4 %13, %17, off offset:320 sc0\n\t"
      "global_load_dwordx4 %14, %17, off offset:384 sc0\n\t"
      "global_load_dwordx4 %15, %17, off offset:448 sc0\n\t"
      "s_waitcnt vmcnt(0)"
      : "=&v"(a[0]), "=&v"(a[1]), "=&v"(a[2]), "=&v"(a[3]),
        "=&v"(a[4]), "=&v"(a[5]), "=&v"(a[6]), "=&v"(a[7]),
        "=&v"(a[8]), "=&v"(a[9]), "=&v"(a[10]), "=&v"(a[11]),
        "=&v"(a[12]), "=&v"(a[13]), "=&v"(a[14]), "=&v"(a[15])
      : "v"(p0), "v"(p1)
      : "memory");
}

// Fast flag sample with deliberate L1 set eviction. Mechanism (explains r2/r3/r4/r8):
// sc0 loads are served by L1 when the line is resident; a flag line re-read forever is
// never evicted -> permanently stale (r3 hang, r8 null). Fix: 6 dummy sc0 reads at
// flag+k*8KB (same L1 set under 4/8KB set-period indexing; wrapped in the 64KB flag
// region), drain, then the sc0 flag read -> the sample reflects the XCD L2, where the
// producer's plain store provably lands (r2 h-transport).
__device__ __forceinline__ unsigned sample_flag_evict(const unsigned* fp, const char* fb) {
  const u64 off = (u64)((const char*)fp - fb);
  const unsigned* p1 = (const unsigned*)(fb + ((off + 1u * 8192u) & 0xFFFFu));
  const unsigned* p2 = (const unsigned*)(fb + ((off + 2u * 8192u) & 0xFFFFu));
  const unsigned* p3 = (const unsigned*)(fb + ((off + 3u * 8192u) & 0xFFFFu));
  const unsigned* p4 = (const unsigned*)(fb + ((off + 4u * 8192u) & 0xFFFFu));
  const unsigned* p5 = (const unsigned*)(fb + ((off + 5u * 8192u) & 0xFFFFu));
  const unsigned* p6 = (const unsigned*)(fb + ((off + 6u * 8192u) & 0xFFFFu));
  unsigned d0, d1, d2, d3, d4, d5, v;
  asm volatile(
      "global_load_dword %0, %7, off sc0\n\t"
      "global_load_dword %1, %8, off sc0\n\t"
      "global_load_dword %2, %9, off sc0\n\t"
      "global_load_dword %3, %10, off sc0\n\t"
      "global_load_dword %4, %11, off sc0\n\t"
      "global_load_dword %5, %12, off sc0\n\t"
      "s_waitcnt vmcnt(0)\n\t"
      "global_load_dword %6, %13, off sc0\n\t"
      "s_waitcnt vmcnt(0)"
      : "=&v"(d0), "=&v"(d1), "=&v"(d2), "=&v"(d3), "=&v"(d4), "=&v"(d5), "=&v"(v)
      : "v"(p1), "v"(p2), "v"(p3), "v"(p4), "v"(p5), "v"(p6), "v"(fp)
      : "memory");
  return v;
}

// Dual-channel group barrier (32 WGs). Slot = 256B; word0 = FAST flag (plain store ->
// XCD L2, r2 transport); word32 (+128B, separate line) = agent fallback (r6 transport).
// Producers always dual-post (r8-proven, no hang). LOCAL poll: 3 evict+sc0 fast samples
// per 1 agent fallback sample (k&3); best=max of both monotone channels, predicate
// >= thr -> stale fast samples can never release early; the agent samples bound
// liveness at <=4x r6's proven period. !LOCAL: agent-only poll of word32.
// Thresholds r6-verbatim: L0 waits L0 slots >= e, L1 slots >= e-1 (3-buffer h1 slack);
// L1 waits all >= e.
template <int LAYER, bool LOCAL>
__device__ __forceinline__ void group_barrier(unsigned* slots, const char* fbase,
                                              int role, unsigned e, int tid) {
  __syncthreads();
  __atomic_signal_fence(__ATOMIC_SEQ_CST);
  if (tid == 0) {
    *(volatile unsigned*)(slots + role * 64) = e;  // fast: plain -> L2
    __hip_atomic_store(slots + role * 64 + 32, e, __ATOMIC_RELAXED,
                       __HIP_MEMORY_SCOPE_AGENT);  // fallback
  }
  if (tid < 64) {
    const int s = tid & 31;
    const unsigned thr = (LAYER == 0 && s >= 16) ? e - 1u : e;
    if constexpr (LOCAL) {
      unsigned best = 0;
      for (int k = 0;; ++k) {
        unsigned v = ((k & 3) == 3)
            ? __hip_atomic_load(slots + s * 64 + 32, __ATOMIC_RELAXED,
                                __HIP_MEMORY_SCOPE_AGENT)
            : sample_flag_evict(slots + s * 64, fbase);
        best = v > best ? v : best;
        if (__all(best >= thr)) break;
        __builtin_amdgcn_s_sleep(1);
      }
    } else {
      for (;;) {
        unsigned v = __hip_atomic_load(slots + s * 64 + 32, __ATOMIC_RELAXED,
                                       __HIP_MEMORY_SCOPE_AGENT);
        if (__all(v >= thr)) break;
        __builtin_amdgcn_s_sleep(2);
      }
    }
  }
  __atomic_signal_fence(__ATOMIC_SEQ_CST);
  __syncthreads();
}

// One LSTM layer's persistent loop — r6-verbatim except the barrier:
// 8 groups x (16 L0-WG + 16 L1-WG); group owns 32 batch rows; WG owns 16 units.
// h1 triple-buffered (write i%3, read (i+2)%3), h2 double-buffered. LOCAL: plain h
// stores + sc0 h loads (r2-proven). !LOCAL: agent data path. Gs stride 68.
template <int LAYER, bool LOCAL>
__device__ void run_layer(const float* __restrict__ xin, const f16* __restrict__ in2base,
                          const float* __restrict__ Wih, const float* __restrict__ Whh,
                          const float* __restrict__ bias, f16* __restrict__ hself,
                          unsigned* slots, const char* fbase, int role, int ng, int b0r,
                          float (*Gs)[68], int tid) {
  constexpr int NCH = (LAYER == 0) ? 12 : 16;
  constexpr int DIN = (LAYER == 0) ? 128 : 256;

  const int lane = tid & 63, wave = tid >> 6;
  const int q = lane >> 4, mm = lane & 15;
  const int rw = wave & 1, uw = wave >> 1;
  const int u0 = ng * 16 + uw * 8;

  // epilogue mapping: each thread owns 1 batch row x 2 adjacent units (4B store)
  const int up_e = tid & 7, bl_e = tid >> 3;          // unit pair 0..7, batch row 0..31
  const int uwe = up_e >> 2, ppe = up_e & 3;
  const int uc0 = ng * 16 + uwe * 8 + 2 * ppe, uc1 = uc0 + 1;
  const int gcol = uwe * 32 + 2 * ppe;                // col of gate i in Gs
  const float bi0 = bias[uc0],       bi1 = bias[uc1];
  const float bf0 = bias[256 + uc0], bf1 = bias[256 + uc1];
  const float bg0 = bias[512 + uc0], bg1 = bias[512 + uc1];
  const float bo0 = bias[768 + uc0], bo1 = bias[768 + uc1];

  // B-fragment preload: B[k=(lane>>4)*8+j][n=lane&15], W row = gate*256 + unit
  const int row0 = ((mm >> 3)) * 256 + u0 + (mm & 7);      // gates i,f
  const int row1 = ((mm >> 3) + 2) * 256 + u0 + (mm & 7);  // gates g,o
  f16x8 bA[NCH], bB[NCH];
#pragma unroll
  for (int c = 0; c < NCH; ++c) {
    const int k0 = c * 32 + q * 8;
    const float* s0 = (c < 8) ? (Whh + row0 * 256 + k0) : (Wih + row0 * DIN + (k0 - 256));
    const float* s1 = (c < 8) ? (Whh + row1 * 256 + k0) : (Wih + row1 * DIN + (k0 - 256));
    f16x8 v0, v1;
#pragma unroll
    for (int j = 0; j < 8; ++j) { v0[j] = (f16)s0[j]; v1[j] = (f16)s1[j]; }
    bA[c] = v0; bB[c] = v1;
  }

  float cA = 0.f, cB = 0.f;  // cell state for the 2 owned units, registers
  const int brow = b0r + rw * 16 + mm;

  float4 axr[8];   // raw fp32 x for the NEXT step (loaded 1 iter ahead)
  f16x8 ax[4];     // fp16 x fragments for the CURRENT step

  for (int it = 0; it <= TT + 1; ++it) {
    const int i = it - 1;
    const bool active = (LAYER == 0) ? (i >= 0 && i < TT) : (i >= 1 && i <= TT);

    if (LAYER == 0 && active) {
      // convert last iteration's raw x (drained at the intervening barrier)
#pragma unroll
      for (int c = 0; c < 4; ++c) {
        const float4 fa = axr[2 * c], fb = axr[2 * c + 1];
        f16x8 v; v[0]=(f16)fa.x; v[1]=(f16)fa.y; v[2]=(f16)fa.z; v[3]=(f16)fa.w;
        v[4]=(f16)fb.x; v[5]=(f16)fb.y; v[6]=(f16)fb.z; v[7]=(f16)fb.w;
        ax[c] = v;
      }
    }

    f16x8 a[NCH];
    if (active) {
      // L0: own h1, 3-buffer, read (i+2)%3.  L1: own h2 2-buffer; input h1 (i+2)%3.
      const f16* hprev = (LAYER == 0) ? (hself + ((i + 2) % 3) * 65536)
                                      : (hself + ((i + 1) & 1) * 65536);
      const f16* pa1 = hprev + brow * 256 + q * 8;
      if (LAYER == 0) {
        if constexpr (LOCAL) load_h8_sc0(pa1, a);
        else {
#pragma unroll
          for (int c = 0; c < 8; ++c) a[c] = load_frag_agent(pa1 + c * 32);
        }
#pragma unroll
        for (int c = 8; c < NCH; ++c) a[c] = ax[c - 8];
      } else {
        const f16* pa2 = in2base + ((i + 2) % 3) * 65536 + brow * 256 + q * 8;
        if constexpr (LOCAL) load_h16_sc0(pa1, pa2, a);
        else {
#pragma unroll
          for (int c = 0; c < 8; ++c) a[c] = load_frag_agent(pa1 + c * 32);
#pragma unroll
          for (int c = 8; c < NCH; ++c) a[c] = load_frag_agent(pa2 + (c - 8) * 32);
        }
      }
    }

    // issue raw x loads for step `it` (consumed next iteration); issued AFTER the
    // h-load wait so they stay in flight across MFMA/epilogue/barrier.
    if (LAYER == 0 && it < TT) {
      const float* px = xin + (brow * 1024 + it) * 128 + q * 8;
#pragma unroll
      for (int c = 0; c < 4; ++c) {
        axr[2 * c]     = *(const float4*)(px + c * 32);
        axr[2 * c + 1] = *(const float4*)(px + c * 32 + 4);
      }
    }

    if (active) {
      f32x4 acc0 = {0.f, 0.f, 0.f, 0.f}, acc1 = {0.f, 0.f, 0.f, 0.f};
#pragma unroll
      for (int c = 0; c < NCH; ++c) {
        acc0 = __builtin_amdgcn_mfma_f32_16x16x32_f16(a[c], bA[c], acc0, 0, 0, 0);
        acc1 = __builtin_amdgcn_mfma_f32_16x16x32_f16(a[c], bB[c], acc1, 0, 0, 0);
      }
      // C/D layout: col=lane&15 (gate unit), row=(lane>>4)*4+reg (batch)
      // Gs stride 68: epilogue reads 2-way (free), writes <=2-way.
#pragma unroll
      for (int r = 0; r < 4; ++r) {
        Gs[rw * 16 + q * 4 + r][uw * 32 + mm] = acc0[r];
        Gs[rw * 16 + q * 4 + r][uw * 32 + 16 + mm] = acc1[r];
      }
      __syncthreads();
      {
        f16* hout = (LAYER == 0) ? (hself + (i % 3) * 65536)
                                 : (hself + (i & 1) * 65536);
        const float gi0 = Gs[bl_e][gcol]      + bi0, gi1 = Gs[bl_e][gcol + 1]  + bi1;
        const float gf0 = Gs[bl_e][gcol + 8]  + bf0, gf1 = Gs[bl_e][gcol + 9]  + bf1;
        const float gg0 = Gs[bl_e][gcol + 16] + bg0, gg1 = Gs[bl_e][gcol + 17] + bg1;
        const float go0 = Gs[bl_e][gcol + 24] + bo0, go1 = Gs[bl_e][gcol + 25] + bo1;
        cA = sigmoidf_(gf0) * cA + sigmoidf_(gi0) * tanhf_(gg0);
        cB = sigmoidf_(gf1) * cB + sigmoidf_(gi1) * tanhf_(gg1);
        union { f16 h2v[2]; unsigned u; } pk;
        pk.h2v[0] = (f16)(sigmoidf_(go0) * tanhf_(cA));
        pk.h2v[1] = (f16)(sigmoidf_(go1) * tanhf_(cB));
        unsigned* dst = (unsigned*)(hout + (b0r + bl_e) * 256 + uc0);
        if constexpr (LOCAL) {
          // plain write-through store: lands in own-XCD L2; drained (vmcnt 0) by the
          // barrier's __syncthreads BEFORE both flag stores => release-ordered.
          *dst = pk.u;
        } else {
          __hip_atomic_store(dst, pk.u, __ATOMIC_RELAXED, __HIP_MEMORY_SCOPE_AGENT);
        }
      }
    }

    if (it <= TT)
      group_barrier<LAYER, LOCAL>(slots, fbase, role, (unsigned)(it + 1), tid);
  }
}

__global__ __launch_bounds__(256, 1) void lstm_persistent(
    const float* __restrict__ x,
    const float* __restrict__ Wih0, const float* __restrict__ Whh0, const float* __restrict__ b0v,
    const float* __restrict__ Wih1, const float* __restrict__ Whh1, const float* __restrict__ b1v,
    f16* h1buf, f16* h2buf, unsigned* F) {
  __shared__ float Gs[32][68];
  __shared__ int sh[3];
  const int tid = threadIdx.x;

  // ---- XCD self-organization (r2/r6-proven). NG (9 u32) at F+64KB (r8-proven page,
  // clear of all slot lines incl. the +128B fallback words). Zeroed by extended memset.
  if (tid == 0) {
    // HW_REG_XCC_ID = hwreg id 20, offset 0, size 32 -> imm = 20 | (31<<11) = 63508
    unsigned xcc = __builtin_amdgcn_s_getreg(63508) & 7u;
    unsigned* NG = F + 16384;
    unsigned rank = __hip_atomic_fetch_add(&NG[xcc], 1u, __ATOMIC_RELAXED, __HIP_MEMORY_SCOPE_AGENT);
    __hip_atomic_fetch_add(&NG[8], 1u, __ATOMIC_RELEASE, __HIP_MEMORY_SCOPE_AGENT);
    while (__hip_atomic_load(&NG[8], __ATOMIC_ACQUIRE, __HIP_MEMORY_SCOPE_AGENT) < 256u)
      __builtin_amdgcn_s_sleep(8);
    unsigned cnt[8];
#pragma unroll
    for (int xx = 0; xx < 8; ++xx)
      cnt[xx] = __hip_atomic_load(&NG[xx], __ATOMIC_RELAXED, __HIP_MEMORY_SCOPE_AGENT);
    int group, role2;
    if (rank < 32u) {
      group = (int)xcc; role2 = (int)rank;
    } else {
      // deterministic overflow assignment: my overflow index -> j-th deficit slot
      int ov = (int)rank - 32;
      for (int xx = 0; xx < (int)xcc; ++xx) ov += max(0, (int)cnt[xx] - 32);
      int gg = 0, acc = 0;
      for (gg = 0; gg < 8; ++gg) {
        const int d = 32 - min(32, (int)cnt[gg]);
        if (ov < acc + d) break;
        acc += d;
      }
      if (gg > 7) gg = 7;
      group = gg; role2 = min(31, (int)cnt[gg] + (ov - acc));
    }
    sh[0] = group; sh[1] = role2; sh[2] = (cnt[group] >= 32u) ? 1 : 0;  // fully local?
  }
  __syncthreads();
  const int group = sh[0], role = sh[1], local = sh[2];
  unsigned* slots = F + group * 2048;   // 32 slots x 64 u32 (256B apart) per group
  const char* fbase = (const char*)F;   // 64KB flag region (eviction-stride window)
  const int b0r = group * 32;
  const int layer = role >> 4, ng = role & 15;

  if (layer == 0) {
    if (local) run_layer<0, true >(x, nullptr, Wih0, Whh0, b0v, h1buf, slots, fbase, role, ng, b0r, Gs, tid);
    else       run_layer<0, false>(x, nullptr, Wih0, Whh0, b0v, h1buf, slots, fbase, role, ng, b0r, Gs, tid);
  } else {
    if (local) run_layer<1, true >(nullptr, h1buf, Wih1, Whh1, b1v, h2buf, slots, fbase, role, ng, b0r, Gs, tid);
    else       run_layer<1, false>(nullptr, h1buf, Wih1, Whh1, b1v, h2buf, slots, fbase, role, ng, b0r, Gs, tid);
  }
}

// final dense (C=10) + softmax on h2[T-1]; one wave per batch row.
// (kernel-end release flushes dirty h lines; standard inter-kernel visibility.)
__global__ __launch_bounds__(64, 1) void dense_softmax_k(const f16* __restrict__ h2,
                                                         const float* __restrict__ Wd,
                                                         const float* __restrict__ bd,
                                                         float* __restrict__ out) {
  const int b = blockIdx.x, lane = threadIdx.x;
  float hv[4];
#pragma unroll
  for (int j = 0; j < 4; ++j) hv[j] = (float)h2[b * 256 + lane + 64 * j];
  float p[10];
#pragma unroll
  for (int c = 0; c < 10; ++c) {
    float s = 0.f;
#pragma unroll
    for (int j = 0; j < 4; ++j) s += hv[j] * Wd[c * 256 + lane + 64 * j];
#pragma unroll
    for (int off = 32; off >= 1; off >>= 1) s += __shfl_xor(s, off, 64);
    p[c] = s;
  }
  if (lane == 0) {
    float mx = -1e30f;
#pragma unroll
    for (int c = 0; c < 10; ++c) { p[c] += bd[c]; mx = fmaxf(mx, p[c]); }
    float den = 0.f;
#pragma unroll
    for (int c = 0; c < 10; ++c) { p[c] = __expf(p[c] - mx); den += p[c]; }
#pragma unroll
    for (int c = 0; c < 10; ++c) out[b * 10 + c] = p[c] / den;
  }
}

extern "C" void kernel_launch(void* const* d_in, const int* in_sizes, int n_in,
                              void* d_out, int out_size, void* d_ws, size_t ws_size,
                              hipStream_t stream) {
  const float* x    = (const float*)d_in[0];
  const float* Wih0 = (const float*)d_in[1];
  const float* Whh0 = (const float*)d_in[2];
  const float* b0v  = (const float*)d_in[3];
  const float* Wih1 = (const float*)d_in[4];
  const float* Whh1 = (const float*)d_in[5];
  const float* b1v  = (const float*)d_in[6];
  const float* Wd   = (const float*)d_in[7];
  const float* bd   = (const float*)d_in[8];

  char* ws = (char*)d_ws;
  // layout: h1buf[3] @0 (384KB) | h2buf[2] @384K (256KB) | flags @640K (64KB) | NG @704K
  f16* h1buf = (f16*)(ws);
  f16* h2buf = (f16*)(ws + 384 * 1024);
  unsigned* F = (unsigned*)(ws + 640 * 1024);

  // zero h1 buffer 2 (initial h1[-1], @256K) + h2 buffer 0 (initial h2 state, @384K)
  // -> contiguous 256KB; and flags (64KB) + NG page (4KB).
  hipMemsetAsync(ws + 256 * 1024, 0, 256 * 1024, stream);
  hipMemsetAsync(ws + 640 * 1024, 0, 68 * 1024, stream);

  lstm_persistent<<<256, 256, 0, stream>>>(x, Wih0, Whh0, b0v, Wih1, Whh1, b1v,
                                           h1buf, h2buf, F);
  // h2[T-1] lands in h2buf[0] (T even)
  dense_softmax_k<<<256, 64, 0, stream>>>(h2buf, Wd, bd, (float*)d_out);
}